// Round 5
// baseline (6636.625 us; speedup 1.0000x reference)
//
#include <hip/hip_runtime.h>
#include <math.h>

// DistillerGRU: T=512, B=64, H=1024, 2 layers.
// R5: persistent cooperative kernel, layers pipelined (skew 1).
//  - Weights resident in VGPRs (48 half8/wave), loaded once.
//  - h exchanged via relaxed agent-scope (L3-coherent) atomics; x16 via plain
//    L2-cached loads.
//  - Masterless flat barrier: 256 per-WG epoch slots (plain epoch stores, no
//    RMW); every WG's wave0 scans all slots (4/lane) + __ballot. One hop.
//  - y32 stores handed via LDS to waves 2/3, issued after arrive (overlapped
//    with poll). Final barrier trimmed; fast tanh.

#define TT 512
#define BB 64
#define HH 1024
#define NWG 256
#define NBH (BB * HH)

typedef _Float16 half8 __attribute__((ext_vector_type(8)));
typedef _Float16 f16x4 __attribute__((ext_vector_type(4)));
typedef float f32x4 __attribute__((ext_vector_type(4)));
typedef unsigned long long u64_t;

// ---------------- f32 -> f16 conversion ----------------
__global__ void cvt_f32_f16_kernel(const float* __restrict__ src,
                                   _Float16* __restrict__ dst, long n) {
  long i = ((long)blockIdx.x * blockDim.x + threadIdx.x) * 4;
  long stride = (long)gridDim.x * blockDim.x * 4;
  for (long e = i; e < n; e += stride) {
    float4 v = *(const float4*)(src + e);
    f16x4 h;
    h.x = (_Float16)v.x; h.y = (_Float16)v.y;
    h.z = (_Float16)v.z; h.w = (_Float16)v.w;
    *(f16x4*)(dst + e) = h;
  }
}

// ---------------- weight pack: [Wh | Wx] -> fragment-contiguous ----------------
// wp[tile(192)][kst(64)][lane(64)][8]; element = W[tile*16+(lane&15)][k],
// k = kst*32 + (lane>>4)*8 + sub; kst<32 from Wh, kst>=32 from Wx.
__global__ void cvt_wpack_kernel(const float* __restrict__ Wh,
                                 const float* __restrict__ Wx,
                                 _Float16* __restrict__ wp) {
  int gid = blockIdx.x * 256 + threadIdx.x;   // 192*64*64 threads
  int lane = gid & 63;
  int kst = (gid >> 6) & 63;
  int tile = gid >> 12;
  int g = tile * 16 + (lane & 15);
  int ko = (lane >> 4) * 8;
  const float* src = (kst < 32) ? (Wh + (long)g * HH + kst * 32 + ko)
                                : (Wx + (long)g * HH + (kst - 32) * 32 + ko);
  half8 h;
#pragma unroll
  for (int j = 0; j < 8; ++j) h[j] = (_Float16)src[j];
  *(half8*)(wp + (((long)tile * 64 + kst) * 64 + lane) * 8) = h;
}

// ---------------- h init ----------------
__global__ void init_hf_kernel(const float* __restrict__ h0,
                               _Float16* __restrict__ h0f,
                               _Float16* __restrict__ h1f) {
  int i = blockIdx.x * 256 + threadIdx.x;  // grid = 2*B*H/256
  const int n = NBH;
  float v = h0[i];
  if (i < n) h0f[i] = (_Float16)v;               // layer0 slot 0
  else       h1f[n + (i - n)] = (_Float16)v;     // layer1 slot 1
}

__global__ void sentinel_kernel(float* out) { out[0] = 12345.0f; }

__device__ inline float fast_sigmoid(float x) {
  return 1.f / (1.f + __expf(-x));
}
__device__ inline float fast_tanh(float x) {
  float e = __expf(2.f * x);           // inf for large x -> returns 1; 0 -> -1
  return 1.f - 2.f / (e + 1.f);
}

// ---------------- persistent 2-layer GRU ----------------
__global__ __launch_bounds__(256, 1) void gru_persist(
    const _Float16* __restrict__ x16,
    const _Float16* __restrict__ w0p, const _Float16* __restrict__ w1p,
    const float* __restrict__ bx0, const float* __restrict__ bh0,
    const float* __restrict__ bx1, const float* __restrict__ bh1,
    const float* __restrict__ h0in,
    _Float16* __restrict__ h0f, _Float16* __restrict__ h1f,
    float* __restrict__ out, unsigned* __restrict__ bar)
{
  const int tid = threadIdx.x;
  const int wid = tid >> 6, lane = tid & 63;
  const int wg = blockIdx.x;
  const int layer = wg >> 7;
  const int rb_ = wg & 127;
  const int c = rb_ >> 1;           // col-group 0..63
  const int brow = (rb_ & 1) * 32;  // batch half
  const int lcol = lane & 15;
  const int lk = (lane >> 4) * 8;

  const _Float16* wf = layer ? w1p : w0p;
  const float* bx = layer ? bx1 : bx0;
  const float* bhp = layer ? bh1 : bh0;
  _Float16* hbuf = layer ? h1f : h0f;

  const int col = c * 16 + lcol;
  const float rbv = bhp[col] + bx[col];
  const float zbv = bhp[HH + col] + bx[HH + col];
  const float nhb = bhp[2 * HH + col];
  const float nxb = bx[2 * HH + col];

  // ---- weights resident in VGPRs: wave wid covers kst = wid*16 .. wid*16+15 ----
  half8 wb[3][16];
#pragma unroll
  for (int g = 0; g < 3; ++g) {
    const long tile = (long)(g * 64 + c);
#pragma unroll
    for (int i = 0; i < 16; ++i)
      wb[g][i] = *(const half8*)(wf + (tile * 64 + (wid * 16 + i)) * 512 + lane * 8);
  }

  // f32 h master state (waves 0,1): rows er0..er0+3 at column col
  const int er0 = brow + wid * 16 + (lane >> 4) * 4;
  float hreg[4] = {0.f, 0.f, 0.f, 0.f};
  if (wid < 2) {
#pragma unroll
    for (int j = 0; j < 4; ++j)
      hreg[j] = h0in[layer * NBH + (er0 + j) * HH + col];
  }

  __shared__ f32x4 red[4][2][3][64];
  __shared__ f32x4 yshare[2][64];

  const int kb = (wid & 1) * 512;   // K-base within this wave's source

  // one layer-step phase; assumes barrier (p-1) done. Leaves h stores issued
  // (drained before arrive by caller-side waitcnt inside), y handed to LDS.
  auto do_phase = [&](int p) {
    const int t = p - layer;
    const int rd = p & 1;
    const _Float16* hsrc = hbuf + rd * NBH;
    const _Float16* xsrc = layer ? (h0f + rd * NBH) : (x16 + (long)t * NBH);
    const _Float16* asrc = (wid < 2) ? hsrc : xsrc;

    half8 afr[2][16];
    if (layer == 0 && wid >= 2) {
      // x-half: read-only input, plain L2-cached vector loads
      const _Float16* abase = asrc + (long)(brow + lcol) * HH + kb + lk;
#pragma unroll
      for (int m = 0; m < 2; ++m)
#pragma unroll
        for (int ks = 0; ks < 16; ++ks)
          afr[m][ks] = *(const half8*)(abase + (long)m * 16 * HH + ks * 32);
    } else {
      // h data: L3-coherent bypass loads (written by other XCDs last phase)
      const u64_t* abase = (const u64_t*)(asrc + (long)(brow + lcol) * HH + kb + lk);
      u64_t av[2][16][2];
#pragma unroll
      for (int m = 0; m < 2; ++m)
#pragma unroll
        for (int ks = 0; ks < 16; ++ks) {
          const u64_t* q = abase + m * 4096 + ks * 8;
          av[m][ks][0] = __hip_atomic_load(q,     __ATOMIC_RELAXED, __HIP_MEMORY_SCOPE_AGENT);
          av[m][ks][1] = __hip_atomic_load(q + 1, __ATOMIC_RELAXED, __HIP_MEMORY_SCOPE_AGENT);
        }
#pragma unroll
      for (int m = 0; m < 2; ++m)
#pragma unroll
        for (int ks = 0; ks < 16; ++ks) {
          union { u64_t u[2]; half8 h; } cv;
          cv.u[0] = av[m][ks][0]; cv.u[1] = av[m][ks][1];
          afr[m][ks] = cv.h;
        }
    }

    f32x4 acc[2][3] = {};
#pragma unroll
    for (int m = 0; m < 2; ++m)
#pragma unroll
      for (int ks = 0; ks < 16; ++ks)
#pragma unroll
        for (int g = 0; g < 3; ++g)
          acc[m][g] = __builtin_amdgcn_mfma_f32_16x16x32_f16(afr[m][ks], wb[g][ks], acc[m][g], 0, 0, 0);

#pragma unroll
    for (int m = 0; m < 2; ++m)
#pragma unroll
      for (int g = 0; g < 3; ++g)
        red[wid][m][g][lane] = acc[m][g];
    __syncthreads();   // (A)

    if (wid < 2) {
      const int m = wid;
      f32x4 rs = red[0][m][0][lane] + red[1][m][0][lane] + red[2][m][0][lane] + red[3][m][0][lane];
      f32x4 zs = red[0][m][1][lane] + red[1][m][1][lane] + red[2][m][1][lane] + red[3][m][1][lane];
      f32x4 nh = red[0][m][2][lane] + red[1][m][2][lane];
      f32x4 nx = red[2][m][2][lane] + red[3][m][2][lane];
      _Float16* hdst = hbuf + (rd ^ 1) * NBH;
      f32x4 hnv;
#pragma unroll
      for (int j = 0; j < 4; ++j) {
        const float rg = fast_sigmoid(rs[j] + rbv);
        const float zg = fast_sigmoid(zs[j] + zbv);
        const float ng = fast_tanh(nx[j] + nxb + rg * (nh[j] + nhb));
        const float hn = (1.f - zg) * ng + zg * hreg[j];
        hreg[j] = hn;
        hnv[j] = hn;
      }
      if (layer) yshare[wid][lane] = hnv;   // hand y to waves 2/3
#pragma unroll
      for (int j = 0; j < 4; ++j) {
        const int row = er0 + j;
        _Float16 hf = (_Float16)hnv[j];
        unsigned us = (unsigned)__builtin_bit_cast(unsigned short, hf);
        unsigned other = (unsigned)__shfl_xor((int)us, 1);
        if ((lane & 1) == 0) {
          unsigned packed = us | (other << 16);
          __hip_atomic_store((unsigned*)&hdst[row * HH + col], packed,
                             __ATOMIC_RELAXED, __HIP_MEMORY_SCOPE_AGENT);
        }
      }
    }
    asm volatile("s_waitcnt vmcnt(0)" ::: "memory");  // h stores drained
    __syncthreads();   // (B) yshare visible; all h stores of this WG done
  };

  auto store_y = [&](int p) {   // waves 2/3, after arrive: overlapped with poll
    if (layer && wid >= 2) {
      const int t = p - 1;
      const int m = wid - 2;
      f32x4 v = yshare[m][lane];
      const int row0 = brow + m * 16 + (lane >> 4) * 4;
      float* yo = out + (long)t * NBH;
#pragma unroll
      for (int j = 0; j < 4; ++j) yo[(row0 + j) * HH + col] = v[j];
    }
  };

  for (int p = 0; p < TT; ++p) {
    const bool act = layer ? (p >= 1) : true;
    if (act) do_phase(p);
    // ---- arrive: plain epoch store to own slot ----
    const unsigned ep = (unsigned)(p + 1);
    if (tid == 0)
      __hip_atomic_store(bar + wg, ep, __ATOMIC_RELAXED, __HIP_MEMORY_SCOPE_AGENT);
    if (act) store_y(p);
    // ---- detect: wave0 scans all 256 slots ----
    if (p < TT - 1 || layer) {
      if (tid < 64) {
        const unsigned* sl = bar + tid * 4;
        for (;;) {
          unsigned s0 = __hip_atomic_load(sl + 0, __ATOMIC_RELAXED, __HIP_MEMORY_SCOPE_AGENT);
          unsigned s1 = __hip_atomic_load(sl + 1, __ATOMIC_RELAXED, __HIP_MEMORY_SCOPE_AGENT);
          unsigned s2 = __hip_atomic_load(sl + 2, __ATOMIC_RELAXED, __HIP_MEMORY_SCOPE_AGENT);
          unsigned s3 = __hip_atomic_load(sl + 3, __ATOMIC_RELAXED, __HIP_MEMORY_SCOPE_AGENT);
          bool ok = (s0 >= ep) && (s1 >= ep) && (s2 >= ep) && (s3 >= ep);
          if (__ballot(ok) == 0xFFFFFFFFFFFFFFFFull) break;
          __builtin_amdgcn_s_sleep(2);
        }
      }
      __syncthreads();   // (C)
    }
  }

  // layer1: final step (phase TT) needs no trailing barrier
  if (layer) {
    do_phase(TT);
    store_y(TT);
  }

  // final hidden states (f32 master)
  if (wid < 2) {
#pragma unroll
    for (int j = 0; j < 4; ++j)
      out[(long)TT * NBH + layer * NBH + (er0 + j) * HH + col] = hreg[j];
  }
}

// ---------------- launch ----------------
extern "C" void kernel_launch(void* const* d_in, const int* in_sizes, int n_in,
                              void* d_out, int out_size, void* d_ws, size_t ws_size,
                              hipStream_t stream) {
  const float* x   = (const float*)d_in[0];
  const float* h0  = (const float*)d_in[1];
  const float* Wx0 = (const float*)d_in[2];
  const float* bx0 = (const float*)d_in[3];
  const float* Wh0 = (const float*)d_in[4];
  const float* bh0 = (const float*)d_in[5];
  const float* Wx1 = (const float*)d_in[6];
  const float* bx1 = (const float*)d_in[7];
  const float* Wh1 = (const float*)d_in[8];
  const float* bh1 = (const float*)d_in[9];
  float* out = (float*)d_out;

  const long nTBH = (long)TT * BB * HH;
  const long nWP  = (long)192 * 64 * 64 * 8;

  char* p = (char*)d_ws;
  _Float16* x16 = (_Float16*)p;  p += nTBH * 2;     // 67.1 MB
  _Float16* w0p = (_Float16*)p;  p += nWP * 2;      // 12.6 MB
  _Float16* w1p = (_Float16*)p;  p += nWP * 2;      // 12.6 MB
  _Float16* h0f = (_Float16*)p;  p += 2 * (long)NBH * 2;
  _Float16* h1f = (_Float16*)p;  p += 2 * (long)NBH * 2;
  unsigned* bar = (unsigned*)p;  p += 4096;
  if ((size_t)(p - (char*)d_ws) > ws_size) {
    sentinel_kernel<<<1, 1, 0, stream>>>(out);
    return;
  }

  hipMemsetAsync(bar, 0, 4096, stream);
  cvt_f32_f16_kernel<<<2048, 256, 0, stream>>>(x, x16, nTBH);
  cvt_wpack_kernel<<<3072, 256, 0, stream>>>(Wh0, Wx0, w0p);
  cvt_wpack_kernel<<<3072, 256, 0, stream>>>(Wh1, Wx1, w1p);
  init_hf_kernel<<<512, 256, 0, stream>>>(h0, h0f, h1f);

  void* args[] = {(void*)&x16, (void*)&w0p, (void*)&w1p,
                  (void*)&bx0, (void*)&bh0, (void*)&bx1, (void*)&bh1,
                  (void*)&h0, (void*)&h0f, (void*)&h1f,
                  (void*)&out, (void*)&bar};
  hipError_t e = hipLaunchCooperativeKernel((const void*)gru_persist,
                                            dim3(NWG), dim3(256), args, 0, stream);
  if (e != hipSuccess) {
    gru_persist<<<NWG, 256, 0, stream>>>(x16, w0p, w1p, bx0, bh0, bx1, bh1,
                                         h0, h0f, h1f, out, bar);
  }
}

// Round 6
// 5051.528 us; speedup vs baseline: 1.3138x; 1.3138x over previous
//
#include <hip/hip_runtime.h>
#include <math.h>

// DistillerGRU: T=512, B=64, H=1024, 2 layers.
// R6: persistent cooperative kernel, NO global barrier. 4 independent sync
// groups of 64 WGs: (layer, batch-half). Per-WG epoch flags (64B-strided
// slots), ballot-scan detect. L0->L1 coupling via 32-slot h0 history ring
// (L0 never waits on L1 except lazy ring back-pressure at distance 30).
// Weights in VGPRs; h exchanged via relaxed agent-scope (L3) atomics;
// x16 plain L2 loads. x-half waves overlap their loads+MFMAs with h-poll.

#define TT 512
#define BB 64
#define HH 1024
#define NWG 256
#define NBH (BB * HH)
#define RING 32

typedef _Float16 half8 __attribute__((ext_vector_type(8)));
typedef _Float16 f16x4 __attribute__((ext_vector_type(4)));
typedef float f32x4 __attribute__((ext_vector_type(4)));
typedef unsigned long long u64_t;

// ---------------- f32 -> f16 conversion ----------------
__global__ void cvt_f32_f16_kernel(const float* __restrict__ src,
                                   _Float16* __restrict__ dst, long n) {
  long i = ((long)blockIdx.x * blockDim.x + threadIdx.x) * 4;
  long stride = (long)gridDim.x * blockDim.x * 4;
  for (long e = i; e < n; e += stride) {
    float4 v = *(const float4*)(src + e);
    f16x4 h;
    h.x = (_Float16)v.x; h.y = (_Float16)v.y;
    h.z = (_Float16)v.z; h.w = (_Float16)v.w;
    *(f16x4*)(dst + e) = h;
  }
}

// ---------------- weight pack: [Wh | Wx] -> fragment-contiguous ----------------
// wp[tile(192)][kst(64)][lane(64)][8]; element = W[tile*16+(lane&15)][k],
// k = kst*32 + (lane>>4)*8 + sub; kst<32 from Wh, kst>=32 from Wx.
__global__ void cvt_wpack_kernel(const float* __restrict__ Wh,
                                 const float* __restrict__ Wx,
                                 _Float16* __restrict__ wp) {
  int gid = blockIdx.x * 256 + threadIdx.x;   // 192*64*64 threads
  int lane = gid & 63;
  int kst = (gid >> 6) & 63;
  int tile = gid >> 12;
  int g = tile * 16 + (lane & 15);
  int ko = (lane >> 4) * 8;
  const float* src = (kst < 32) ? (Wh + (long)g * HH + kst * 32 + ko)
                                : (Wx + (long)g * HH + (kst - 32) * 32 + ko);
  half8 h;
#pragma unroll
  for (int j = 0; j < 8; ++j) h[j] = (_Float16)src[j];
  *(half8*)(wp + (((long)tile * 64 + kst) * 64 + lane) * 8) = h;
}

// ---------------- h init: h0 -> hist slot0 (L0) and h1b slot0 (L1) ----------------
__global__ void init_hf_kernel(const float* __restrict__ h0,
                               _Float16* __restrict__ hist0,
                               _Float16* __restrict__ h1b) {
  int i = blockIdx.x * 256 + threadIdx.x;  // grid = 2*B*H/256
  const int n = NBH;
  float v = h0[i];
  if (i < n) hist0[i] = (_Float16)v;
  else       h1b[i - n] = (_Float16)v;
}

__global__ void sentinel_kernel(float* out) { out[0] = 12345.0f; }

__device__ inline float fast_sigmoid(float x) { return 1.f / (1.f + __expf(-x)); }
__device__ inline float fast_tanh(float x) {
  float e = __expf(2.f * x);
  return 1.f - 2.f / (e + 1.f);
}

// ---------------- persistent 2-layer GRU ----------------
__global__ __launch_bounds__(256, 1) void gru_persist(
    const _Float16* __restrict__ x16,
    const _Float16* __restrict__ w0p, const _Float16* __restrict__ w1p,
    const float* __restrict__ bx0, const float* __restrict__ bh0,
    const float* __restrict__ bx1, const float* __restrict__ bh1,
    const float* __restrict__ h0in,
    _Float16* __restrict__ hist,   // [RING][B][H] fp16 h0 history ring
    _Float16* __restrict__ h1b,    // [2][B][H] fp16 h1 double buffer
    float* __restrict__ out, unsigned* __restrict__ bar)
{
  const int tid = threadIdx.x;
  const int wid = tid >> 6, lane = tid & 63;
  const int wg = blockIdx.x;
  const int layer = wg >> 7;
  const int idx = wg & 127;
  const int c = idx >> 1;           // col-group 0..63
  const int bh = idx & 1;           // batch half
  const int brow = bh * 32;
  const int lcol = lane & 15;
  const int lk = (lane >> 4) * 8;

  const _Float16* wf = layer ? w1p : w0p;

  // flags: group g occupies 4KB (64 slots x 64B stride) -> spread over L3
  unsigned* myf = bar + (layer * 2 + bh) * 1024;
  unsigned* l0f = bar + bh * 1024;             // producer group (L0, same half)
  unsigned* l1f = bar + (2 + bh) * 1024;       // consumer group (L1, same half)

  // ---- weights resident: wave wid covers kst = wid*16 .. wid*16+15 ----
  half8 wb[3][16];
#pragma unroll
  for (int g = 0; g < 3; ++g) {
    const long tile = (long)(g * 64 + c);
#pragma unroll
    for (int i = 0; i < 16; ++i)
      wb[g][i] = *(const half8*)(wf + (tile * 64 + (wid * 16 + i)) * 512 + lane * 8);
  }

  const int col = c * 16 + lcol;
  const int er0 = brow + wid * 16 + (lane >> 4) * 4;
  float rbv = 0.f, zbv = 0.f, nhb = 0.f, nxb = 0.f;
  float hreg[4] = {0.f, 0.f, 0.f, 0.f};
  if (wid < 2) {
    const float* bx = layer ? bx1 : bx0;
    const float* bhp = layer ? bh1 : bh0;
    rbv = bhp[col] + bx[col];
    zbv = bhp[HH + col] + bx[HH + col];
    nhb = bhp[2 * HH + col];
    nxb = bx[2 * HH + col];
#pragma unroll
    for (int j = 0; j < 4; ++j)
      hreg[j] = h0in[layer * NBH + (er0 + j) * HH + col];
  }

  __shared__ f32x4 red[4][2][3][64];
  __shared__ f32x4 yshare[2][64];

  int lb = 0;   // lazy lower bound on consumer (L1) progress, for ring reuse

  for (int t = 0; t < TT; ++t) {
    const int rd = t & 1;
    half8 afr[2][16];

    if (wid < 2) {
      // ---- wait: own group finished step t-1 ----
      if (t > 0) {
        for (;;) {
          int f = (int)__hip_atomic_load(myf + lane * 16, __ATOMIC_RELAXED, __HIP_MEMORY_SCOPE_AGENT);
          if (__ballot(f >= t) == ~0ull) break;
          __builtin_amdgcn_s_sleep(1);
        }
      }
      // ---- ring back-pressure: L1 must have consumed old slot (lazy) ----
      if (layer == 0 && t >= RING - 1) {
        const int need = t - (RING - 2);
        while (lb < need) {
          int f = (int)__hip_atomic_load(l1f + lane * 16, __ATOMIC_RELAXED, __HIP_MEMORY_SCOPE_AGENT);
          if (__ballot(f >= need) == ~0ull) lb = need;
          else __builtin_amdgcn_s_sleep(1);
        }
      }
      asm volatile("" ::: "memory");
      // ---- h-load (L3-coherent) ----
      const _Float16* hsrc = layer ? (h1b + (long)rd * NBH)
                                   : (hist + (long)(t & (RING - 1)) * NBH);
      const u64_t* ab = (const u64_t*)(hsrc + (long)(brow + lcol) * HH + wid * 512 + lk);
      u64_t av[2][16][2];
#pragma unroll
      for (int m = 0; m < 2; ++m)
#pragma unroll
        for (int ks = 0; ks < 16; ++ks) {
          const u64_t* q = ab + m * 4096 + ks * 8;
          av[m][ks][0] = __hip_atomic_load(q,     __ATOMIC_RELAXED, __HIP_MEMORY_SCOPE_AGENT);
          av[m][ks][1] = __hip_atomic_load(q + 1, __ATOMIC_RELAXED, __HIP_MEMORY_SCOPE_AGENT);
        }
#pragma unroll
      for (int m = 0; m < 2; ++m)
#pragma unroll
        for (int ks = 0; ks < 16; ++ks) {
          union { u64_t u[2]; half8 h; } cv;
          cv.u[0] = av[m][ks][0]; cv.u[1] = av[m][ks][1];
          afr[m][ks] = cv.h;
        }
    } else {
      const int xb = (wid & 1) * 512;
      if (layer == 0) {
        // static input: plain L2-cached loads, no waiting at all
        const _Float16* abase = x16 + (long)t * NBH + (long)(brow + lcol) * HH + xb + lk;
#pragma unroll
        for (int m = 0; m < 2; ++m)
#pragma unroll
          for (int ks = 0; ks < 16; ++ks)
            afr[m][ks] = *(const half8*)(abase + (long)m * 16 * HH + ks * 32);
      } else {
        // y0[t] = h0 state t+1: wait on producer group
        for (;;) {
          int f = (int)__hip_atomic_load(l0f + lane * 16, __ATOMIC_RELAXED, __HIP_MEMORY_SCOPE_AGENT);
          if (__ballot(f >= t + 1) == ~0ull) break;
          __builtin_amdgcn_s_sleep(1);
        }
        asm volatile("" ::: "memory");
        const _Float16* ysrc = hist + (long)((t + 1) & (RING - 1)) * NBH;
        const u64_t* ab = (const u64_t*)(ysrc + (long)(brow + lcol) * HH + xb + lk);
        u64_t av[2][16][2];
#pragma unroll
        for (int m = 0; m < 2; ++m)
#pragma unroll
          for (int ks = 0; ks < 16; ++ks) {
            const u64_t* q = ab + m * 4096 + ks * 8;
            av[m][ks][0] = __hip_atomic_load(q,     __ATOMIC_RELAXED, __HIP_MEMORY_SCOPE_AGENT);
            av[m][ks][1] = __hip_atomic_load(q + 1, __ATOMIC_RELAXED, __HIP_MEMORY_SCOPE_AGENT);
          }
#pragma unroll
        for (int m = 0; m < 2; ++m)
#pragma unroll
          for (int ks = 0; ks < 16; ++ks) {
            union { u64_t u[2]; half8 h; } cv;
            cv.u[0] = av[m][ks][0]; cv.u[1] = av[m][ks][1];
            afr[m][ks] = cv.h;
          }
      }
    }

    // ---- MFMA: 96 per wave ----
    f32x4 acc[2][3] = {};
#pragma unroll
    for (int m = 0; m < 2; ++m)
#pragma unroll
      for (int ks = 0; ks < 16; ++ks)
#pragma unroll
        for (int g = 0; g < 3; ++g)
          acc[m][g] = __builtin_amdgcn_mfma_f32_16x16x32_f16(afr[m][ks], wb[g][ks], acc[m][g], 0, 0, 0);
#pragma unroll
    for (int m = 0; m < 2; ++m)
#pragma unroll
      for (int g = 0; g < 3; ++g)
        red[wid][m][g][lane] = acc[m][g];
    __syncthreads();   // (A)

    if (wid < 2) {
      const int m = wid;
      f32x4 rs = red[0][m][0][lane] + red[1][m][0][lane] + red[2][m][0][lane] + red[3][m][0][lane];
      f32x4 zs = red[0][m][1][lane] + red[1][m][1][lane] + red[2][m][1][lane] + red[3][m][1][lane];
      f32x4 nh = red[0][m][2][lane] + red[1][m][2][lane];
      f32x4 nx = red[2][m][2][lane] + red[3][m][2][lane];
      _Float16* hdst = layer ? (h1b + (long)(rd ^ 1) * NBH)
                             : (hist + (long)((t + 1) & (RING - 1)) * NBH);
      f32x4 hnv;
#pragma unroll
      for (int j = 0; j < 4; ++j) {
        const float rg = fast_sigmoid(rs[j] + rbv);
        const float zg = fast_sigmoid(zs[j] + zbv);
        const float ng = fast_tanh(nx[j] + nxb + rg * (nh[j] + nhb));
        const float hn = (1.f - zg) * ng + zg * hreg[j];
        hreg[j] = hn;
        hnv[j] = hn;
      }
      if (layer) yshare[wid][lane] = hnv;
#pragma unroll
      for (int j = 0; j < 4; ++j) {
        const int row = er0 + j;
        _Float16 hf = (_Float16)hnv[j];
        unsigned us = (unsigned)__builtin_bit_cast(unsigned short, hf);
        unsigned other = (unsigned)__shfl_xor((int)us, 1);
        if ((lane & 1) == 0) {
          unsigned packed = us | (other << 16);
          __hip_atomic_store((unsigned*)&hdst[row * HH + col], packed,
                             __ATOMIC_RELAXED, __HIP_MEMORY_SCOPE_AGENT);
        }
      }
      asm volatile("s_waitcnt vmcnt(0)" ::: "memory");   // h visible at L3
    }
    __syncthreads();   // (B)
    if (tid == 0)
      __hip_atomic_store(myf + c * 16, (unsigned)(t + 1),
                         __ATOMIC_RELAXED, __HIP_MEMORY_SCOPE_AGENT);
    if (layer && wid >= 2) {
      // y output store (off critical path, overlaps next step's poll)
      const int m = wid - 2;
      f32x4 v = yshare[m][lane];
      const int row0 = brow + m * 16 + (lane >> 4) * 4;
      float* yo = out + (long)t * NBH;
#pragma unroll
      for (int j = 0; j < 4; ++j) yo[(row0 + j) * HH + col] = v[j];
    }
  }

  // final hidden states (f32 master)
  if (wid < 2) {
#pragma unroll
    for (int j = 0; j < 4; ++j)
      out[(long)TT * NBH + layer * NBH + (er0 + j) * HH + col] = hreg[j];
  }
}

// ---------------- launch ----------------
extern "C" void kernel_launch(void* const* d_in, const int* in_sizes, int n_in,
                              void* d_out, int out_size, void* d_ws, size_t ws_size,
                              hipStream_t stream) {
  const float* x   = (const float*)d_in[0];
  const float* h0  = (const float*)d_in[1];
  const float* Wx0 = (const float*)d_in[2];
  const float* bx0 = (const float*)d_in[3];
  const float* Wh0 = (const float*)d_in[4];
  const float* bh0 = (const float*)d_in[5];
  const float* Wx1 = (const float*)d_in[6];
  const float* bx1 = (const float*)d_in[7];
  const float* Wh1 = (const float*)d_in[8];
  const float* bh1 = (const float*)d_in[9];
  float* out = (float*)d_out;

  const long nTBH = (long)TT * BB * HH;
  const long nWP  = (long)192 * 64 * 64 * 8;

  char* p = (char*)d_ws;
  _Float16* x16  = (_Float16*)p;  p += nTBH * 2;              // 67.1 MB
  _Float16* w0p  = (_Float16*)p;  p += nWP * 2;               // 12.6 MB
  _Float16* w1p  = (_Float16*)p;  p += nWP * 2;               // 12.6 MB
  _Float16* hist = (_Float16*)p;  p += (long)RING * NBH * 2;  // 4.2 MB
  _Float16* h1b  = (_Float16*)p;  p += 2 * (long)NBH * 2;     // 0.26 MB
  unsigned* bar  = (unsigned*)p;  p += 16384;                 // 4 groups x 4KB
  if ((size_t)(p - (char*)d_ws) > ws_size) {
    sentinel_kernel<<<1, 1, 0, stream>>>(out);
    return;
  }

  hipMemsetAsync(bar, 0, 16384, stream);
  cvt_f32_f16_kernel<<<2048, 256, 0, stream>>>(x, x16, nTBH);
  cvt_wpack_kernel<<<3072, 256, 0, stream>>>(Wh0, Wx0, w0p);
  cvt_wpack_kernel<<<3072, 256, 0, stream>>>(Wh1, Wx1, w1p);
  init_hf_kernel<<<512, 256, 0, stream>>>(h0, hist, h1b);

  void* args[] = {(void*)&x16, (void*)&w0p, (void*)&w1p,
                  (void*)&bx0, (void*)&bh0, (void*)&bx1, (void*)&bh1,
                  (void*)&h0, (void*)&hist, (void*)&h1b,
                  (void*)&out, (void*)&bar};
  hipError_t e = hipLaunchCooperativeKernel((const void*)gru_persist,
                                            dim3(NWG), dim3(256), args, 0, stream);
  if (e != hipSuccess) {
    gru_persist<<<NWG, 256, 0, stream>>>(x16, w0p, w1p, bx0, bh0, bx1, bh1,
                                         h0, hist, h1b, out, bar);
  }
}

// Round 7
// 5003.211 us; speedup vs baseline: 1.3265x; 1.0097x over previous
//
#include <hip/hip_runtime.h>
#include <math.h>

// DistillerGRU: T=512, B=64, H=1024, 2 layers.
// R7 = R6 + poll-traffic reduction (theory: agent-scope poll gathers congest
// L3 and inflate all latencies).
//  - One global poller per wait condition (wave0: own group; wave2: producer
//    group in L1); other waves spin on an LDS epoch (no L3 traffic).
//  - Exponential backoff in global polls (s_sleep 1,2,4, cap 8).
//  - Ring back-pressure check moved to wave3 and made truly lazy (+16 jump).
// Everything else identical to R6: 4 self-paced groups of 64 WGs
// (layer x batch-half), per-WG epoch flags, weights in VGPRs, h via relaxed
// agent-scope (L3) atomics, x16 via plain L2 loads, 32-slot h0 history ring.

#define TT 512
#define BB 64
#define HH 1024
#define NWG 256
#define NBH (BB * HH)
#define RING 32

typedef _Float16 half8 __attribute__((ext_vector_type(8)));
typedef _Float16 f16x4 __attribute__((ext_vector_type(4)));
typedef float f32x4 __attribute__((ext_vector_type(4)));
typedef unsigned long long u64_t;

// ---------------- f32 -> f16 conversion ----------------
__global__ void cvt_f32_f16_kernel(const float* __restrict__ src,
                                   _Float16* __restrict__ dst, long n) {
  long i = ((long)blockIdx.x * blockDim.x + threadIdx.x) * 4;
  long stride = (long)gridDim.x * blockDim.x * 4;
  for (long e = i; e < n; e += stride) {
    float4 v = *(const float4*)(src + e);
    f16x4 h;
    h.x = (_Float16)v.x; h.y = (_Float16)v.y;
    h.z = (_Float16)v.z; h.w = (_Float16)v.w;
    *(f16x4*)(dst + e) = h;
  }
}

// ---------------- weight pack: [Wh | Wx] -> fragment-contiguous ----------------
// wp[tile(192)][kst(64)][lane(64)][8]; element = W[tile*16+(lane&15)][k],
// k = kst*32 + (lane>>4)*8 + sub; kst<32 from Wh, kst>=32 from Wx.
__global__ void cvt_wpack_kernel(const float* __restrict__ Wh,
                                 const float* __restrict__ Wx,
                                 _Float16* __restrict__ wp) {
  int gid = blockIdx.x * 256 + threadIdx.x;   // 192*64*64 threads
  int lane = gid & 63;
  int kst = (gid >> 6) & 63;
  int tile = gid >> 12;
  int g = tile * 16 + (lane & 15);
  int ko = (lane >> 4) * 8;
  const float* src = (kst < 32) ? (Wh + (long)g * HH + kst * 32 + ko)
                                : (Wx + (long)g * HH + (kst - 32) * 32 + ko);
  half8 h;
#pragma unroll
  for (int j = 0; j < 8; ++j) h[j] = (_Float16)src[j];
  *(half8*)(wp + (((long)tile * 64 + kst) * 64 + lane) * 8) = h;
}

// ---------------- h init: h0 -> hist slot0 (L0) and h1b slot0 (L1) ----------------
__global__ void init_hf_kernel(const float* __restrict__ h0,
                               _Float16* __restrict__ hist0,
                               _Float16* __restrict__ h1b) {
  int i = blockIdx.x * 256 + threadIdx.x;  // grid = 2*B*H/256
  const int n = NBH;
  float v = h0[i];
  if (i < n) hist0[i] = (_Float16)v;
  else       h1b[i - n] = (_Float16)v;
}

__global__ void sentinel_kernel(float* out) { out[0] = 12345.0f; }

__device__ inline float fast_sigmoid(float x) { return 1.f / (1.f + __expf(-x)); }
__device__ inline float fast_tanh(float x) {
  float e = __expf(2.f * x);
  return 1.f - 2.f / (e + 1.f);
}

__device__ inline void backoff_sleep(int sl) {
  if (sl == 0) __builtin_amdgcn_s_sleep(1);
  else if (sl == 1) __builtin_amdgcn_s_sleep(2);
  else if (sl == 2) __builtin_amdgcn_s_sleep(4);
  else __builtin_amdgcn_s_sleep(8);
}

// ---------------- persistent 2-layer GRU ----------------
__global__ __launch_bounds__(256, 1) void gru_persist(
    const _Float16* __restrict__ x16,
    const _Float16* __restrict__ w0p, const _Float16* __restrict__ w1p,
    const float* __restrict__ bx0, const float* __restrict__ bh0,
    const float* __restrict__ bx1, const float* __restrict__ bh1,
    const float* __restrict__ h0in,
    _Float16* __restrict__ hist,   // [RING][B][H] fp16 h0 history ring
    _Float16* __restrict__ h1b,    // [2][B][H] fp16 h1 double buffer
    float* __restrict__ out, unsigned* __restrict__ bar)
{
  const int tid = threadIdx.x;
  const int wid = tid >> 6, lane = tid & 63;
  const int wg = blockIdx.x;
  const int layer = wg >> 7;
  const int idx = wg & 127;
  const int c = idx >> 1;           // col-group 0..63 (slot id within group)
  const int bh = idx & 1;           // batch half
  const int brow = bh * 32;
  const int lcol = lane & 15;
  const int lk = (lane >> 4) * 8;

  const _Float16* wf = layer ? w1p : w0p;

  // flags: group g occupies 4KB (64 slots x 64B stride)
  unsigned* myf = bar + (layer * 2 + bh) * 1024;
  unsigned* l0f = bar + bh * 1024;             // producer group (L0, same half)
  unsigned* l1f = bar + (2 + bh) * 1024;       // consumer group (L1, same half)

  // ---- weights resident: wave wid covers kst = wid*16 .. wid*16+15 ----
  half8 wb[3][16];
#pragma unroll
  for (int g = 0; g < 3; ++g) {
    const long tile = (long)(g * 64 + c);
#pragma unroll
    for (int i = 0; i < 16; ++i)
      wb[g][i] = *(const half8*)(wf + (tile * 64 + (wid * 16 + i)) * 512 + lane * 8);
  }

  const int col = c * 16 + lcol;
  const int er0 = brow + wid * 16 + (lane >> 4) * 4;
  float rbv = 0.f, zbv = 0.f, nhb = 0.f, nxb = 0.f;
  float hreg[4] = {0.f, 0.f, 0.f, 0.f};
  if (wid < 2) {
    const float* bx = layer ? bx1 : bx0;
    const float* bhp = layer ? bh1 : bh0;
    rbv = bhp[col] + bx[col];
    zbv = bhp[HH + col] + bx[HH + col];
    nhb = bhp[2 * HH + col];
    nxb = bx[2 * HH + col];
#pragma unroll
    for (int j = 0; j < 4; ++j)
      hreg[j] = h0in[layer * NBH + (er0 + j) * HH + col];
  }

  __shared__ f32x4 red[4][2][3][64];
  __shared__ f32x4 yshare[2][64];
  __shared__ unsigned rdy[2];    // [0]: own-group epoch, [1]: producer epoch
  if (tid == 0) { rdy[0] = 0; rdy[1] = 0; }
  __syncthreads();

  int lb = 0;   // wave3(L0): lazy lower bound on consumer (L1) progress

  for (int t = 0; t < TT; ++t) {
    const int rd = t & 1;
    half8 afr[2][16];

    if (wid < 2) {
      // ---- wait: own group finished step t-1 (wave0 polls, wave1 LDS-spins) ----
      if (t > 0) {
        if (wid == 0) {
          int sl = 0;
          for (;;) {
            int f = (int)__hip_atomic_load(myf + lane * 16, __ATOMIC_RELAXED, __HIP_MEMORY_SCOPE_AGENT);
            if (__ballot(f >= t) == ~0ull) break;
            backoff_sleep(sl); ++sl;
          }
          if (lane == 0)
            __hip_atomic_store(&rdy[0], (unsigned)t, __ATOMIC_RELEASE, __HIP_MEMORY_SCOPE_WORKGROUP);
        } else {
          while (__hip_atomic_load(&rdy[0], __ATOMIC_ACQUIRE, __HIP_MEMORY_SCOPE_WORKGROUP) < (unsigned)t)
            __builtin_amdgcn_s_sleep(1);
        }
        asm volatile("" ::: "memory");
      }
      // ---- h-load (L3-coherent) ----
      const _Float16* hsrc = layer ? (h1b + (long)rd * NBH)
                                   : (hist + (long)(t & (RING - 1)) * NBH);
      const u64_t* ab = (const u64_t*)(hsrc + (long)(brow + lcol) * HH + wid * 512 + lk);
      u64_t av[2][16][2];
#pragma unroll
      for (int m = 0; m < 2; ++m)
#pragma unroll
        for (int ks = 0; ks < 16; ++ks) {
          const u64_t* q = ab + m * 4096 + ks * 8;
          av[m][ks][0] = __hip_atomic_load(q,     __ATOMIC_RELAXED, __HIP_MEMORY_SCOPE_AGENT);
          av[m][ks][1] = __hip_atomic_load(q + 1, __ATOMIC_RELAXED, __HIP_MEMORY_SCOPE_AGENT);
        }
#pragma unroll
      for (int m = 0; m < 2; ++m)
#pragma unroll
        for (int ks = 0; ks < 16; ++ks) {
          union { u64_t u[2]; half8 h; } cv;
          cv.u[0] = av[m][ks][0]; cv.u[1] = av[m][ks][1];
          afr[m][ks] = cv.h;
        }
    } else {
      const int xb = (wid & 1) * 512;
      if (layer == 0) {
        // ring back-pressure (wave3, truly lazy: jump lb forward by +16)
        if (wid == 3 && t >= RING - 1) {
          const int need = t - (RING - 1);
          if (lb < need) {
            int sl = 0;
            for (;;) {
              int f = (int)__hip_atomic_load(l1f + lane * 16, __ATOMIC_RELAXED, __HIP_MEMORY_SCOPE_AGENT);
              if (__ballot(f >= need + 16) == ~0ull) { lb = need + 16; break; }
              if (__ballot(f >= need) == ~0ull) { lb = need; break; }
              backoff_sleep(sl); ++sl;
            }
          }
        }
        // static input: plain L2-cached loads, no waiting
        const _Float16* abase = x16 + (long)t * NBH + (long)(brow + lcol) * HH + xb + lk;
#pragma unroll
        for (int m = 0; m < 2; ++m)
#pragma unroll
          for (int ks = 0; ks < 16; ++ks)
            afr[m][ks] = *(const half8*)(abase + (long)m * 16 * HH + ks * 32);
      } else {
        // y0[t] = h0 state t+1: wave2 polls producer flags, wave3 LDS-spins
        if (wid == 2) {
          int sl = 0;
          for (;;) {
            int f = (int)__hip_atomic_load(l0f + lane * 16, __ATOMIC_RELAXED, __HIP_MEMORY_SCOPE_AGENT);
            if (__ballot(f >= t + 1) == ~0ull) break;
            backoff_sleep(sl); ++sl;
          }
          if (lane == 0)
            __hip_atomic_store(&rdy[1], (unsigned)(t + 1), __ATOMIC_RELEASE, __HIP_MEMORY_SCOPE_WORKGROUP);
        } else {
          while (__hip_atomic_load(&rdy[1], __ATOMIC_ACQUIRE, __HIP_MEMORY_SCOPE_WORKGROUP) < (unsigned)(t + 1))
            __builtin_amdgcn_s_sleep(1);
        }
        asm volatile("" ::: "memory");
        const _Float16* ysrc = hist + (long)((t + 1) & (RING - 1)) * NBH;
        const u64_t* ab = (const u64_t*)(ysrc + (long)(brow + lcol) * HH + xb + lk);
        u64_t av[2][16][2];
#pragma unroll
        for (int m = 0; m < 2; ++m)
#pragma unroll
          for (int ks = 0; ks < 16; ++ks) {
            const u64_t* q = ab + m * 4096 + ks * 8;
            av[m][ks][0] = __hip_atomic_load(q,     __ATOMIC_RELAXED, __HIP_MEMORY_SCOPE_AGENT);
            av[m][ks][1] = __hip_atomic_load(q + 1, __ATOMIC_RELAXED, __HIP_MEMORY_SCOPE_AGENT);
          }
#pragma unroll
        for (int m = 0; m < 2; ++m)
#pragma unroll
          for (int ks = 0; ks < 16; ++ks) {
            union { u64_t u[2]; half8 h; } cv;
            cv.u[0] = av[m][ks][0]; cv.u[1] = av[m][ks][1];
            afr[m][ks] = cv.h;
          }
      }
    }

    // ---- MFMA: 96 per wave ----
    f32x4 acc[2][3] = {};
#pragma unroll
    for (int m = 0; m < 2; ++m)
#pragma unroll
      for (int ks = 0; ks < 16; ++ks)
#pragma unroll
        for (int g = 0; g < 3; ++g)
          acc[m][g] = __builtin_amdgcn_mfma_f32_16x16x32_f16(afr[m][ks], wb[g][ks], acc[m][g], 0, 0, 0);
#pragma unroll
    for (int m = 0; m < 2; ++m)
#pragma unroll
      for (int g = 0; g < 3; ++g)
        red[wid][m][g][lane] = acc[m][g];
    __syncthreads();   // (A)

    if (wid < 2) {
      const int m = wid;
      f32x4 rs = red[0][m][0][lane] + red[1][m][0][lane] + red[2][m][0][lane] + red[3][m][0][lane];
      f32x4 zs = red[0][m][1][lane] + red[1][m][1][lane] + red[2][m][1][lane] + red[3][m][1][lane];
      f32x4 nh = red[0][m][2][lane] + red[1][m][2][lane];
      f32x4 nx = red[2][m][2][lane] + red[3][m][2][lane];
      _Float16* hdst = layer ? (h1b + (long)(rd ^ 1) * NBH)
                             : (hist + (long)((t + 1) & (RING - 1)) * NBH);
      f32x4 hnv;
#pragma unroll
      for (int j = 0; j < 4; ++j) {
        const float rg = fast_sigmoid(rs[j] + rbv);
        const float zg = fast_sigmoid(zs[j] + zbv);
        const float ng = fast_tanh(nx[j] + nxb + rg * (nh[j] + nhb));
        const float hn = (1.f - zg) * ng + zg * hreg[j];
        hreg[j] = hn;
        hnv[j] = hn;
      }
      if (layer) yshare[wid][lane] = hnv;
#pragma unroll
      for (int j = 0; j < 4; ++j) {
        const int row = er0 + j;
        _Float16 hf = (_Float16)hnv[j];
        unsigned us = (unsigned)__builtin_bit_cast(unsigned short, hf);
        unsigned other = (unsigned)__shfl_xor((int)us, 1);
        if ((lane & 1) == 0) {
          unsigned packed = us | (other << 16);
          __hip_atomic_store((unsigned*)&hdst[row * HH + col], packed,
                             __ATOMIC_RELAXED, __HIP_MEMORY_SCOPE_AGENT);
        }
      }
      asm volatile("s_waitcnt vmcnt(0)" ::: "memory");   // h visible at L3
    }
    __syncthreads();   // (B)
    if (tid == 0)
      __hip_atomic_store(myf + c * 16, (unsigned)(t + 1),
                         __ATOMIC_RELAXED, __HIP_MEMORY_SCOPE_AGENT);
    if (layer && wid >= 2) {
      // y output store (off critical path, overlaps next step's poll)
      const int m = wid - 2;
      f32x4 v = yshare[m][lane];
      const int row0 = brow + m * 16 + (lane >> 4) * 4;
      float* yo = out + (long)t * NBH;
#pragma unroll
      for (int j = 0; j < 4; ++j) yo[(row0 + j) * HH + col] = v[j];
    }
  }

  // final hidden states (f32 master)
  if (wid < 2) {
#pragma unroll
    for (int j = 0; j < 4; ++j)
      out[(long)TT * NBH + layer * NBH + (er0 + j) * HH + col] = hreg[j];
  }
}

// ---------------- launch ----------------
extern "C" void kernel_launch(void* const* d_in, const int* in_sizes, int n_in,
                              void* d_out, int out_size, void* d_ws, size_t ws_size,
                              hipStream_t stream) {
  const float* x   = (const float*)d_in[0];
  const float* h0  = (const float*)d_in[1];
  const float* Wx0 = (const float*)d_in[2];
  const float* bx0 = (const float*)d_in[3];
  const float* Wh0 = (const float*)d_in[4];
  const float* bh0 = (const float*)d_in[5];
  const float* Wx1 = (const float*)d_in[6];
  const float* bx1 = (const float*)d_in[7];
  const float* Wh1 = (const float*)d_in[8];
  const float* bh1 = (const float*)d_in[9];
  float* out = (float*)d_out;

  const long nTBH = (long)TT * BB * HH;
  const long nWP  = (long)192 * 64 * 64 * 8;

  char* p = (char*)d_ws;
  _Float16* x16  = (_Float16*)p;  p += nTBH * 2;              // 67.1 MB
  _Float16* w0p  = (_Float16*)p;  p += nWP * 2;               // 12.6 MB
  _Float16* w1p  = (_Float16*)p;  p += nWP * 2;               // 12.6 MB
  _Float16* hist = (_Float16*)p;  p += (long)RING * NBH * 2;  // 4.2 MB
  _Float16* h1b  = (_Float16*)p;  p += 2 * (long)NBH * 2;     // 0.26 MB
  unsigned* bar  = (unsigned*)p;  p += 16384;                 // 4 groups x 4KB
  if ((size_t)(p - (char*)d_ws) > ws_size) {
    sentinel_kernel<<<1, 1, 0, stream>>>(out);
    return;
  }

  hipMemsetAsync(bar, 0, 16384, stream);
  cvt_f32_f16_kernel<<<2048, 256, 0, stream>>>(x, x16, nTBH);
  cvt_wpack_kernel<<<3072, 256, 0, stream>>>(Wh0, Wx0, w0p);
  cvt_wpack_kernel<<<3072, 256, 0, stream>>>(Wh1, Wx1, w1p);
  init_hf_kernel<<<512, 256, 0, stream>>>(h0, hist, h1b);

  void* args[] = {(void*)&x16, (void*)&w0p, (void*)&w1p,
                  (void*)&bx0, (void*)&bh0, (void*)&bx1, (void*)&bh1,
                  (void*)&h0, (void*)&hist, (void*)&h1b,
                  (void*)&out, (void*)&bar};
  hipError_t e = hipLaunchCooperativeKernel((const void*)gru_persist,
                                            dim3(NWG), dim3(256), args, 0, stream);
  if (e != hipSuccess) {
    gru_persist<<<NWG, 256, 0, stream>>>(x16, w0p, w1p, bx0, bh0, bx1, bh1,
                                         h0, hist, h1b, out, bar);
  }
}